// Round 1
// baseline (759.420 us; speedup 1.0000x reference)
//
#include <hip/hip_runtime.h>
#include <math.h>

#define NN 8192
#define IN_DIM 128
#define THETA_DIM 256
#define OUT_DIM 64

// ws layout (float offsets)
#define WS_SCALE 0
#define WS_SHIFT 128
#define WS_SUM   256
#define WS_SQ    384
#define WS_ROWSUM 512
#define WS_D     8704
#define WS_HN    16896
#define WS_HX    (WS_HN + NN*IN_DIM)          // 8192*128
#define WS_Z     (WS_HX + NN*THETA_DIM)       // 8192*256
#define WS_OBUF  (WS_Z + NN*OUT_DIM)          // 8192*64
// total floats = WS_OBUF + 8192*64 = 4,211,200 (~16.1 MB)

__global__ __launch_bounds__(256) void k_stats(const float* __restrict__ H, float* __restrict__ ws) {
    int tid = threadIdx.x;
    int c = tid & 127, h = tid >> 7;
    int rb = blockIdx.x * 128;
    float s = 0.f, q = 0.f;
    for (int r = h; r < 128; r += 2) {
        float v = H[(size_t)(rb + r) * IN_DIM + c];
        s += v; q += v * v;
    }
    atomicAdd(&ws[WS_SUM + c], s);
    atomicAdd(&ws[WS_SQ + c], q);
}

__global__ void k_finalize(const float* __restrict__ gamma, const float* __restrict__ beta, float* __restrict__ ws) {
    int c = threadIdx.x;  // 128 threads
    float mean = ws[WS_SUM + c] * (1.f / NN);
    float var  = ws[WS_SQ + c] * (1.f / NN) - mean * mean;
    float rstd = 1.f / sqrtf(var + 1e-5f);
    float sc = rstd * gamma[c];
    ws[WS_SCALE + c] = sc;
    ws[WS_SHIFT + c] = beta[c] - mean * sc;
}

__global__ __launch_bounds__(256) void k_hn(const float* __restrict__ H, const float* __restrict__ ws, float* __restrict__ Hn) {
    int i = blockIdx.x * 256 + threadIdx.x;  // f4 index, 262144 total
    const float4* H4 = (const float4*)H;
    float4 v = H4[i];
    int cb = (i & 31) * 4;
    float4 sc = *(const float4*)&ws[WS_SCALE + cb];
    float4 sh = *(const float4*)&ws[WS_SHIFT + cb];
    float4 o;
    o.x = v.x * sc.x + sh.x; o.y = v.y * sc.y + sh.y;
    o.z = v.z * sc.z + sh.z; o.w = v.w * sc.w + sh.w;
    ((float4*)Hn)[i] = o;
}

// Hx = Hn @ W1 + b1   [8192,256] = [8192,128]@[128,256]
__global__ __launch_bounds__(256) void k_hx(const float* __restrict__ Hn, const float* __restrict__ W1,
                                            const float* __restrict__ b1, float* __restrict__ Hx) {
    __shared__ float HnS[32 * IN_DIM];  // 16KB
    int tid = threadIdx.x;
    int row0 = blockIdx.x * 32;
    const float4* src = (const float4*)(Hn + (size_t)row0 * IN_DIM);
    float4* dst = (float4*)HnS;
#pragma unroll
    for (int q = 0; q < 4; q++) dst[q * 256 + tid] = src[q * 256 + tid];
    __syncthreads();
    int c = tid;
    float acc[32];
#pragma unroll
    for (int r = 0; r < 32; r++) acc[r] = 0.f;
    for (int k0 = 0; k0 < IN_DIM; k0 += 4) {
        float w0 = W1[(size_t)(k0 + 0) * THETA_DIM + c];
        float w1 = W1[(size_t)(k0 + 1) * THETA_DIM + c];
        float w2 = W1[(size_t)(k0 + 2) * THETA_DIM + c];
        float w3 = W1[(size_t)(k0 + 3) * THETA_DIM + c];
#pragma unroll
        for (int r = 0; r < 32; r++) {
            float4 h = *(const float4*)&HnS[r * IN_DIM + k0];
            acc[r] += h.x * w0 + h.y * w1 + h.z * w2 + h.w * w3;
        }
    }
    float bb = b1[c];
#pragma unroll
    for (int r = 0; r < 32; r++) Hx[(size_t)(row0 + r) * THETA_DIM + c] = acc[r] + bb;
}

// Y = Hn @ Wout + bout   [8192,64]
__global__ __launch_bounds__(256) void k_y(const float* __restrict__ Hn, const float* __restrict__ Wout,
                                           const float* __restrict__ bout, float* __restrict__ Y) {
    __shared__ float HnS[64 * IN_DIM];  // 32KB
    int tid = threadIdx.x;
    int row0 = blockIdx.x * 64;
    const float4* src = (const float4*)(Hn + (size_t)row0 * IN_DIM);
    float4* dst = (float4*)HnS;
#pragma unroll
    for (int q = 0; q < 8; q++) dst[q * 256 + tid] = src[q * 256 + tid];
    __syncthreads();
    int c = tid & 63, rg = tid >> 6;
    float acc[16];
#pragma unroll
    for (int r = 0; r < 16; r++) acc[r] = 0.f;
    for (int k0 = 0; k0 < IN_DIM; k0 += 4) {
        float w0 = Wout[(size_t)(k0 + 0) * OUT_DIM + c];
        float w1 = Wout[(size_t)(k0 + 1) * OUT_DIM + c];
        float w2 = Wout[(size_t)(k0 + 2) * OUT_DIM + c];
        float w3 = Wout[(size_t)(k0 + 3) * OUT_DIM + c];
#pragma unroll
        for (int r = 0; r < 16; r++) {
            float4 h = *(const float4*)&HnS[(rg * 16 + r) * IN_DIM + k0];
            acc[r] += h.x * w0 + h.y * w1 + h.z * w2 + h.w * w3;
        }
    }
    float bb = bout[c];
#pragma unroll
    for (int r = 0; r < 16; r++) Y[(size_t)(row0 + rg * 16 + r) * OUT_DIM + c] = acc[r] + bb;
}

// scores GEMM + sigmoid + mask + eye + A1 write + rowsum
__global__ __launch_bounds__(256) void k_scores(const float* __restrict__ Hx, const float* __restrict__ Amat,
                                                float* __restrict__ A1, float* __restrict__ rowsum) {
    __shared__ float As[8 * 128];
    __shared__ float Bs[8 * 128];
    __shared__ float red[128 * 17];
    int tid = threadIdx.x;
    int row0 = blockIdx.x * 128, col0 = blockIdx.y * 128;
    int tx = tid & 15, ty = tid >> 4;
    float acc[8][8];
#pragma unroll
    for (int i = 0; i < 8; i++)
#pragma unroll
        for (int j = 0; j < 8; j++) acc[i][j] = 0.f;

    int lr_ = tid >> 1, kq = (tid & 1) * 4;
    const float* pa = Hx + (size_t)(row0 + lr_) * THETA_DIM + kq;
    const float* pb = Hx + (size_t)(col0 + lr_) * THETA_DIM + kq;

    for (int k0 = 0; k0 < THETA_DIM; k0 += 8) {
        float4 av = *(const float4*)(pa + k0);
        float4 bv = *(const float4*)(pb + k0);
        __syncthreads();
        As[(kq + 0) * 128 + lr_] = av.x; As[(kq + 1) * 128 + lr_] = av.y;
        As[(kq + 2) * 128 + lr_] = av.z; As[(kq + 3) * 128 + lr_] = av.w;
        Bs[(kq + 0) * 128 + lr_] = bv.x; Bs[(kq + 1) * 128 + lr_] = bv.y;
        Bs[(kq + 2) * 128 + lr_] = bv.z; Bs[(kq + 3) * 128 + lr_] = bv.w;
        __syncthreads();
#pragma unroll
        for (int k = 0; k < 8; k++) {
            float a[8], b[8];
            *(float4*)&a[0] = *(const float4*)&As[k * 128 + ty * 4];
            *(float4*)&a[4] = *(const float4*)&As[k * 128 + 64 + ty * 4];
            *(float4*)&b[0] = *(const float4*)&Bs[k * 128 + tx * 4];
            *(float4*)&b[4] = *(const float4*)&Bs[k * 128 + 64 + tx * 4];
#pragma unroll
            for (int i = 0; i < 8; i++)
#pragma unroll
                for (int j = 0; j < 8; j++) acc[i][j] += a[i] * b[j];
        }
    }

    // epilogue: sigmoid, mask, eye, write A1, row partial sums
    float rpart[8];
#pragma unroll
    for (int i = 0; i < 8; i++) rpart[i] = 0.f;
#pragma unroll
    for (int i = 0; i < 8; i++) {
        int lr = (i < 4) ? (ty * 4 + i) : (64 + ty * 4 + (i - 4));
        int gi = row0 + lr;
#pragma unroll
        for (int jblk = 0; jblk < 2; jblk++) {
            int gc0 = col0 + jblk * 64 + tx * 4;
            float4 a4 = *(const float4*)&Amat[(size_t)gi * NN + gc0];
            float am[4] = {a4.x, a4.y, a4.z, a4.w};
            float r4[4];
#pragma unroll
            for (int jj = 0; jj < 4; jj++) {
                int j = jblk * 4 + jj;
                float x = acc[i][j];
                float s = 1.f / (1.f + expf(-x));
                float m = ceilf(am[jj] * 1e-5f);
                int gj = gc0 + jj;
                float v = fmaxf(s, 0.1f) * m + ((gi == gj) ? 1.f : 0.f);
                r4[jj] = v;
                rpart[i] += v;
            }
            float4 wv; wv.x = r4[0]; wv.y = r4[1]; wv.z = r4[2]; wv.w = r4[3];
            *(float4*)&A1[(size_t)gi * NN + gc0] = wv;
        }
    }
#pragma unroll
    for (int i = 0; i < 8; i++) {
        int lr = (i < 4) ? (ty * 4 + i) : (64 + ty * 4 + (i - 4));
        red[lr * 17 + tx] = rpart[i];
    }
    __syncthreads();
    if (tid < 128) {
        float s = 0.f;
#pragma unroll
        for (int t = 0; t < 16; t++) s += red[tid * 17 + t];
        atomicAdd(&rowsum[row0 + tid], s);
    }
}

__global__ void k_dvec(float* __restrict__ ws) {
    int i = blockIdx.x * 256 + threadIdx.x;  // 8192
    ws[WS_D + i] = 1.f / sqrtf(ws[WS_ROWSUM + i]);
}

__global__ void k_scalez(float* __restrict__ ws) {
    int i = blockIdx.x * 256 + threadIdx.x;  // f4 over 524288 floats -> 131072
    float4* Z4 = (float4*)&ws[WS_Z];
    int row = i >> 4;
    float d = ws[WS_D + row];
    float4 v = Z4[i];
    v.x *= d; v.y *= d; v.z *= d; v.w *= d;
    Z4[i] = v;
}

// obuf += A1[rows, jrange] @ Zd[jrange, :]
__global__ __launch_bounds__(256) void k_spmm(const float* __restrict__ A1, const float* __restrict__ ws,
                                              float* __restrict__ obuf) {
    __shared__ float AT[64 * 68];   // [jj][row], stride 68 (pad)
    __shared__ float Zs[64 * 64];
    int tid = threadIdx.x;
    int row0 = blockIdx.x * 64;
    int j0 = blockIdx.y * 2048;
    int c = tid & 63, rg = tid >> 6;
    const float* Z = ws + WS_Z;
    float acc[16];
#pragma unroll
    for (int r = 0; r < 16; r++) acc[r] = 0.f;

    for (int jc = j0; jc < j0 + 2048; jc += 64) {
        __syncthreads();
#pragma unroll
        for (int q = 0; q < 4; q++) {
            int f4i = q * 256 + tid;
            int r = f4i >> 4, c4 = (f4i & 15) * 4;
            float4 v = *(const float4*)&A1[(size_t)(row0 + r) * NN + jc + c4];
            AT[(c4 + 0) * 68 + r] = v.x;
            AT[(c4 + 1) * 68 + r] = v.y;
            AT[(c4 + 2) * 68 + r] = v.z;
            AT[(c4 + 3) * 68 + r] = v.w;
        }
#pragma unroll
        for (int q = 0; q < 4; q++) {
            int f4i = q * 256 + tid;
            ((float4*)Zs)[f4i] = *(const float4*)&Z[(size_t)jc * OUT_DIM + f4i * 4];
        }
        __syncthreads();
#pragma unroll 4
        for (int jj = 0; jj < 64; jj++) {
            float zv = Zs[jj * 64 + c];
            float4 a0 = *(const float4*)&AT[jj * 68 + rg * 16 + 0];
            float4 a1 = *(const float4*)&AT[jj * 68 + rg * 16 + 4];
            float4 a2 = *(const float4*)&AT[jj * 68 + rg * 16 + 8];
            float4 a3 = *(const float4*)&AT[jj * 68 + rg * 16 + 12];
            acc[0] += a0.x * zv;  acc[1] += a0.y * zv;  acc[2] += a0.z * zv;  acc[3] += a0.w * zv;
            acc[4] += a1.x * zv;  acc[5] += a1.y * zv;  acc[6] += a1.z * zv;  acc[7] += a1.w * zv;
            acc[8] += a2.x * zv;  acc[9] += a2.y * zv;  acc[10] += a2.z * zv; acc[11] += a2.w * zv;
            acc[12] += a3.x * zv; acc[13] += a3.y * zv; acc[14] += a3.z * zv; acc[15] += a3.w * zv;
        }
    }
#pragma unroll
    for (int r = 0; r < 16; r++)
        atomicAdd(&obuf[(size_t)(row0 + rg * 16 + r) * OUT_DIM + c], acc[r]);
}

__global__ void k_out(const float* __restrict__ ws, float* __restrict__ out) {
    int i = blockIdx.x * 256 + threadIdx.x;  // f4 over 524288 -> 131072
    const float4* O4 = (const float4*)(ws + WS_OBUF);
    int row = i >> 4;
    float d = ws[WS_D + row];
    float4 v = O4[i];
    float a = d * v.x, b = d * v.y, cc = d * v.z, e = d * v.w;
    v.x = (a >= 0.f) ? a : 0.01f * a;
    v.y = (b >= 0.f) ? b : 0.01f * b;
    v.z = (cc >= 0.f) ? cc : 0.01f * cc;
    v.w = (e >= 0.f) ? e : 0.01f * e;
    ((float4*)out)[i] = v;
}

extern "C" void kernel_launch(void* const* d_in, const int* in_sizes, int n_in,
                              void* d_out, int out_size, void* d_ws, size_t ws_size,
                              hipStream_t stream) {
    const float* H     = (const float*)d_in[0];
    const float* A     = (const float*)d_in[1];
    const float* gamma = (const float*)d_in[2];
    const float* beta  = (const float*)d_in[3];
    const float* W1    = (const float*)d_in[4];
    const float* b1    = (const float*)d_in[5];
    const float* Wout  = (const float*)d_in[6];
    const float* bout  = (const float*)d_in[7];
    float* out = (float*)d_out;
    float* A1  = out + (size_t)NN * OUT_DIM;
    float* ws  = (float*)d_ws;

    // zero accumulators: sum/sq/rowsum [256, 8704) and obuf
    hipMemsetAsync(ws + WS_SUM, 0, (WS_D - WS_SUM) * sizeof(float), stream);
    hipMemsetAsync(ws + WS_OBUF, 0, (size_t)NN * OUT_DIM * sizeof(float), stream);

    k_stats<<<64, 256, 0, stream>>>(H, ws);
    k_finalize<<<1, 128, 0, stream>>>(gamma, beta, ws);
    k_hn<<<1024, 256, 0, stream>>>(H, ws, ws + WS_HN);
    k_hx<<<256, 256, 0, stream>>>(ws + WS_HN, W1, b1, ws + WS_HX);
    k_y<<<128, 256, 0, stream>>>(ws + WS_HN, Wout, bout, ws + WS_Z);
    dim3 g6(64, 64);
    k_scores<<<g6, 256, 0, stream>>>(ws + WS_HX, A, A1, ws + WS_ROWSUM);
    k_dvec<<<32, 256, 0, stream>>>(ws);
    k_scalez<<<512, 256, 0, stream>>>(ws);
    k_spmm<<<dim3(128, 4), 256, 0, stream>>>(A1, ws, ws + WS_OBUF);
    k_out<<<512, 256, 0, stream>>>(ws, out);
}

// Round 2
// 611.750 us; speedup vs baseline: 1.2414x; 1.2414x over previous
//
#include <hip/hip_runtime.h>
#include <math.h>

#define NN 8192
#define IN_DIM 128
#define THETA_DIM 256
#define OUT_DIM 64

typedef _Float16 half_t;
typedef _Float16 f16x8 __attribute__((ext_vector_type(8)));
typedef float f32x4 __attribute__((ext_vector_type(4)));

// ws layout (float offsets)
#define WS_SCALE 0
#define WS_SHIFT 128
#define WS_SUM   256
#define WS_SQ    384
#define WS_ROWSUM 512
#define WS_D     8704
#define WS_HN    16896
#define WS_HX    (WS_HN + NN*IN_DIM)          // f16 buffer [8192][256] (occupies 1M float slots)
#define WS_Z     (WS_HX + NN*THETA_DIM)       // 8192*64 f32
#define WS_OBUF  (WS_Z + NN*OUT_DIM)          // 8192*64 f32

__global__ __launch_bounds__(256) void k_stats(const float* __restrict__ H, float* __restrict__ ws) {
    int tid = threadIdx.x;
    int c = tid & 127, h = tid >> 7;
    int rb = blockIdx.x * 128;
    float s = 0.f, q = 0.f;
    for (int r = h; r < 128; r += 2) {
        float v = H[(size_t)(rb + r) * IN_DIM + c];
        s += v; q += v * v;
    }
    atomicAdd(&ws[WS_SUM + c], s);
    atomicAdd(&ws[WS_SQ + c], q);
}

__global__ void k_finalize(const float* __restrict__ gamma, const float* __restrict__ beta, float* __restrict__ ws) {
    int c = threadIdx.x;  // 128 threads
    float mean = ws[WS_SUM + c] * (1.f / NN);
    float var  = ws[WS_SQ + c] * (1.f / NN) - mean * mean;
    float rstd = 1.f / sqrtf(var + 1e-5f);
    float sc = rstd * gamma[c];
    ws[WS_SCALE + c] = sc;
    ws[WS_SHIFT + c] = beta[c] - mean * sc;
}

__global__ __launch_bounds__(256) void k_hn(const float* __restrict__ H, const float* __restrict__ ws, float* __restrict__ Hn) {
    int i = blockIdx.x * 256 + threadIdx.x;  // f4 index, 262144 total
    const float4* H4 = (const float4*)H;
    float4 v = H4[i];
    int cb = (i & 31) * 4;
    float4 sc = *(const float4*)&ws[WS_SCALE + cb];
    float4 sh = *(const float4*)&ws[WS_SHIFT + cb];
    float4 o;
    o.x = v.x * sc.x + sh.x; o.y = v.y * sc.y + sh.y;
    o.z = v.z * sc.z + sh.z; o.w = v.w * sc.w + sh.w;
    ((float4*)Hn)[i] = o;
}

// Hx = (Hn @ W1 + b1) as f16   [8192,256]
__global__ __launch_bounds__(256) void k_hx(const float* __restrict__ Hn, const float* __restrict__ W1,
                                            const float* __restrict__ b1, half_t* __restrict__ Hx) {
    __shared__ float HnS[32 * IN_DIM];  // 16KB
    int tid = threadIdx.x;
    int row0 = blockIdx.x * 32;
    const float4* src = (const float4*)(Hn + (size_t)row0 * IN_DIM);
    float4* dst = (float4*)HnS;
#pragma unroll
    for (int q = 0; q < 4; q++) dst[q * 256 + tid] = src[q * 256 + tid];
    __syncthreads();
    int c = tid;
    float acc[32];
#pragma unroll
    for (int r = 0; r < 32; r++) acc[r] = 0.f;
    for (int k0 = 0; k0 < IN_DIM; k0 += 4) {
        float w0 = W1[(size_t)(k0 + 0) * THETA_DIM + c];
        float w1 = W1[(size_t)(k0 + 1) * THETA_DIM + c];
        float w2 = W1[(size_t)(k0 + 2) * THETA_DIM + c];
        float w3 = W1[(size_t)(k0 + 3) * THETA_DIM + c];
#pragma unroll
        for (int r = 0; r < 32; r++) {
            float4 h = *(const float4*)&HnS[r * IN_DIM + k0];
            acc[r] += h.x * w0 + h.y * w1 + h.z * w2 + h.w * w3;
        }
    }
    float bb = b1[c];
#pragma unroll
    for (int r = 0; r < 32; r++) Hx[(size_t)(row0 + r) * THETA_DIM + c] = (half_t)(acc[r] + bb);
}

// Y = Hn @ Wout + bout   [8192,64]
__global__ __launch_bounds__(256) void k_y(const float* __restrict__ Hn, const float* __restrict__ Wout,
                                           const float* __restrict__ bout, float* __restrict__ Y) {
    __shared__ float HnS[64 * IN_DIM];  // 32KB
    int tid = threadIdx.x;
    int row0 = blockIdx.x * 64;
    const float4* src = (const float4*)(Hn + (size_t)row0 * IN_DIM);
    float4* dst = (float4*)HnS;
#pragma unroll
    for (int q = 0; q < 8; q++) dst[q * 256 + tid] = src[q * 256 + tid];
    __syncthreads();
    int c = tid & 63, rg = tid >> 6;
    float acc[16];
#pragma unroll
    for (int r = 0; r < 16; r++) acc[r] = 0.f;
    for (int k0 = 0; k0 < IN_DIM; k0 += 4) {
        float w0 = Wout[(size_t)(k0 + 0) * OUT_DIM + c];
        float w1 = Wout[(size_t)(k0 + 1) * OUT_DIM + c];
        float w2 = Wout[(size_t)(k0 + 2) * OUT_DIM + c];
        float w3 = Wout[(size_t)(k0 + 3) * OUT_DIM + c];
#pragma unroll
        for (int r = 0; r < 16; r++) {
            float4 h = *(const float4*)&HnS[(rg * 16 + r) * IN_DIM + k0];
            acc[r] += h.x * w0 + h.y * w1 + h.z * w2 + h.w * w3;
        }
    }
    float bb = bout[c];
#pragma unroll
    for (int r = 0; r < 16; r++) Y[(size_t)(row0 + rg * 16 + r) * OUT_DIM + c] = acc[r] + bb;
}

// scores = sigmoid(Hx @ Hx^T) via f16 MFMA; fused mask/eye/A1-write/rowsum.
// 128x128 tile, 4 waves, each wave a 64x64 quadrant (4x4 grid of 16x16x32 MFMA tiles).
__global__ __launch_bounds__(256) void k_scores(const half_t* __restrict__ Hx,
                                                const float* __restrict__ Amat,
                                                float* __restrict__ A1, float* __restrict__ rowsum) {
    __shared__ half_t As[128 * 72];  // padded stride 72 halfs (144 B) -> 2-way-free banks
    __shared__ half_t Bs[128 * 72];
    int tid = threadIdx.x;
    int row0 = blockIdx.x * 128, col0 = blockIdx.y * 128;
    int lane = tid & 63, wv = tid >> 6;
    int li = lane & 15, lg = lane >> 4;
    int qr = (wv >> 1) * 64, qc = (wv & 1) * 64;

    f32x4 acc[4][4];
#pragma unroll
    for (int t = 0; t < 4; t++)
#pragma unroll
        for (int u = 0; u < 4; u++) acc[t][u] = (f32x4){0.f, 0.f, 0.f, 0.f};

    for (int s = 0; s < 4; s++) {
        int k0 = s * 64;
        // reg-stage: 1024 16B-units per panel, 256 threads -> 4 units each
        f16x8 ra[4], rb[4];
#pragma unroll
        for (int q = 0; q < 4; q++) {
            int un = q * 256 + tid;
            int r = un >> 3, u = un & 7;
            ra[q] = *(const f16x8*)(Hx + (size_t)(row0 + r) * THETA_DIM + k0 + u * 8);
            rb[q] = *(const f16x8*)(Hx + (size_t)(col0 + r) * THETA_DIM + k0 + u * 8);
        }
        __syncthreads();
#pragma unroll
        for (int q = 0; q < 4; q++) {
            int un = q * 256 + tid;
            int r = un >> 3, u = un & 7;
            *(f16x8*)(As + r * 72 + u * 8) = ra[q];
            *(f16x8*)(Bs + r * 72 + u * 8) = rb[q];
        }
        __syncthreads();
#pragma unroll
        for (int kk = 0; kk < 2; kk++) {
            f16x8 af[4], bf[4];
#pragma unroll
            for (int t = 0; t < 4; t++)
                af[t] = *(const f16x8*)(As + (qr + t * 16 + li) * 72 + kk * 32 + lg * 8);
#pragma unroll
            for (int u = 0; u < 4; u++)
                bf[u] = *(const f16x8*)(Bs + (qc + u * 16 + li) * 72 + kk * 32 + lg * 8);
#pragma unroll
            for (int t = 0; t < 4; t++)
#pragma unroll
                for (int u = 0; u < 4; u++)
                    acc[t][u] = __builtin_amdgcn_mfma_f32_16x16x32_f16(af[t], bf[u], acc[t][u], 0, 0, 0);
        }
    }

    // epilogue: sigmoid, mask, eye, write A1, rowsum
    float rs[4][4];
#pragma unroll
    for (int t = 0; t < 4; t++)
#pragma unroll
        for (int r = 0; r < 4; r++) rs[t][r] = 0.f;

#pragma unroll
    for (int t = 0; t < 4; t++) {
#pragma unroll
        for (int r = 0; r < 4; r++) {
            int gr = row0 + qr + t * 16 + lg * 4 + r;
#pragma unroll
            for (int u = 0; u < 4; u++) {
                int gc = col0 + qc + u * 16 + li;
                float x = acc[t][u][r];
                float sg = 1.f / (1.f + __expf(-x));
                float m = ceilf(Amat[(size_t)gr * NN + gc] * 1e-5f);
                float v = fmaxf(sg, 0.1f) * m + ((gr == gc) ? 1.f : 0.f);
                A1[(size_t)gr * NN + gc] = v;
                rs[t][r] += v;
            }
        }
    }
#pragma unroll
    for (int t = 0; t < 4; t++) {
#pragma unroll
        for (int r = 0; r < 4; r++) {
            float v = rs[t][r];
            v += __shfl_xor(v, 1, 64);
            v += __shfl_xor(v, 2, 64);
            v += __shfl_xor(v, 4, 64);
            v += __shfl_xor(v, 8, 64);
            if (li == 0) atomicAdd(&rowsum[row0 + qr + t * 16 + lg * 4 + r], v);
        }
    }
}

__global__ void k_dvec(float* __restrict__ ws) {
    int i = blockIdx.x * 256 + threadIdx.x;  // 8192
    ws[WS_D + i] = 1.f / sqrtf(ws[WS_ROWSUM + i]);
}

__global__ void k_scalez(float* __restrict__ ws) {
    int i = blockIdx.x * 256 + threadIdx.x;  // f4 over 524288 floats -> 131072
    float4* Z4 = (float4*)&ws[WS_Z];
    int row = i >> 4;
    float d = ws[WS_D + row];
    float4 v = Z4[i];
    v.x *= d; v.y *= d; v.z *= d; v.w *= d;
    Z4[i] = v;
}

// obuf += A1[rows, jrange] @ Zd[jrange, :]
__global__ __launch_bounds__(256) void k_spmm(const float* __restrict__ A1, const float* __restrict__ ws,
                                              float* __restrict__ obuf) {
    __shared__ float AT[64 * 68];   // [jj][row], stride 68 (pad)
    __shared__ float Zs[64 * 64];
    int tid = threadIdx.x;
    int row0 = blockIdx.x * 64;
    int j0 = blockIdx.y * 2048;
    int c = tid & 63, rg = tid >> 6;
    const float* Z = ws + WS_Z;
    float acc[16];
#pragma unroll
    for (int r = 0; r < 16; r++) acc[r] = 0.f;

    for (int jc = j0; jc < j0 + 2048; jc += 64) {
        __syncthreads();
#pragma unroll
        for (int q = 0; q < 4; q++) {
            int f4i = q * 256 + tid;
            int r = f4i >> 4, c4 = (f4i & 15) * 4;
            float4 v = *(const float4*)&A1[(size_t)(row0 + r) * NN + jc + c4];
            AT[(c4 + 0) * 68 + r] = v.x;
            AT[(c4 + 1) * 68 + r] = v.y;
            AT[(c4 + 2) * 68 + r] = v.z;
            AT[(c4 + 3) * 68 + r] = v.w;
        }
#pragma unroll
        for (int q = 0; q < 4; q++) {
            int f4i = q * 256 + tid;
            ((float4*)Zs)[f4i] = *(const float4*)&Z[(size_t)jc * OUT_DIM + f4i * 4];
        }
        __syncthreads();
#pragma unroll 4
        for (int jj = 0; jj < 64; jj++) {
            float zv = Zs[jj * 64 + c];
            float4 a0 = *(const float4*)&AT[jj * 68 + rg * 16 + 0];
            float4 a1 = *(const float4*)&AT[jj * 68 + rg * 16 + 4];
            float4 a2 = *(const float4*)&AT[jj * 68 + rg * 16 + 8];
            float4 a3 = *(const float4*)&AT[jj * 68 + rg * 16 + 12];
            acc[0] += a0.x * zv;  acc[1] += a0.y * zv;  acc[2] += a0.z * zv;  acc[3] += a0.w * zv;
            acc[4] += a1.x * zv;  acc[5] += a1.y * zv;  acc[6] += a1.z * zv;  acc[7] += a1.w * zv;
            acc[8] += a2.x * zv;  acc[9] += a2.y * zv;  acc[10] += a2.z * zv; acc[11] += a2.w * zv;
            acc[12] += a3.x * zv; acc[13] += a3.y * zv; acc[14] += a3.z * zv; acc[15] += a3.w * zv;
        }
    }
#pragma unroll
    for (int r = 0; r < 16; r++)
        atomicAdd(&obuf[(size_t)(row0 + rg * 16 + r) * OUT_DIM + c], acc[r]);
}

__global__ void k_out(const float* __restrict__ ws, float* __restrict__ out) {
    int i = blockIdx.x * 256 + threadIdx.x;  // f4 over 524288 -> 131072
    const float4* O4 = (const float4*)(ws + WS_OBUF);
    int row = i >> 4;
    float d = ws[WS_D + row];
    float4 v = O4[i];
    float a = d * v.x, b = d * v.y, cc = d * v.z, e = d * v.w;
    v.x = (a >= 0.f) ? a : 0.01f * a;
    v.y = (b >= 0.f) ? b : 0.01f * b;
    v.z = (cc >= 0.f) ? cc : 0.01f * cc;
    v.w = (e >= 0.f) ? e : 0.01f * e;
    ((float4*)out)[i] = v;
}

extern "C" void kernel_launch(void* const* d_in, const int* in_sizes, int n_in,
                              void* d_out, int out_size, void* d_ws, size_t ws_size,
                              hipStream_t stream) {
    const float* H     = (const float*)d_in[0];
    const float* A     = (const float*)d_in[1];
    const float* gamma = (const float*)d_in[2];
    const float* beta  = (const float*)d_in[3];
    const float* W1    = (const float*)d_in[4];
    const float* b1    = (const float*)d_in[5];
    const float* Wout  = (const float*)d_in[6];
    const float* bout  = (const float*)d_in[7];
    float* out = (float*)d_out;
    float* A1  = out + (size_t)NN * OUT_DIM;
    float* ws  = (float*)d_ws;
    half_t* Hx = (half_t*)(ws + WS_HX);

    // zero accumulators: sum/sq/rowsum [256, 8704) and obuf
    hipMemsetAsync(ws + WS_SUM, 0, (WS_D - WS_SUM) * sizeof(float), stream);
    hipMemsetAsync(ws + WS_OBUF, 0, (size_t)NN * OUT_DIM * sizeof(float), stream);

    k_stats<<<64, 256, 0, stream>>>(H, ws);
    k_finalize<<<1, 128, 0, stream>>>(gamma, beta, ws);
    k_hn<<<1024, 256, 0, stream>>>(H, ws, ws + WS_HN);
    k_hx<<<256, 256, 0, stream>>>(ws + WS_HN, W1, b1, Hx);
    k_y<<<128, 256, 0, stream>>>(ws + WS_HN, Wout, bout, ws + WS_Z);
    dim3 g6(64, 64);
    k_scores<<<g6, 256, 0, stream>>>(Hx, A, A1, ws + WS_ROWSUM);
    k_dvec<<<32, 256, 0, stream>>>(ws);
    k_scalez<<<512, 256, 0, stream>>>(ws);
    k_spmm<<<dim3(128, 4), 256, 0, stream>>>(A1, ws, ws + WS_OBUF);
    k_out<<<512, 256, 0, stream>>>(ws, out);
}

// Round 3
// 398.879 us; speedup vs baseline: 1.9039x; 1.5337x over previous
//
#include <hip/hip_runtime.h>
#include <math.h>

#define NN 8192
#define IN_DIM 128
#define THETA_DIM 256
#define OUT_DIM 64

typedef _Float16 half_t;
typedef _Float16 f16x8 __attribute__((ext_vector_type(8)));
typedef _Float16 f16x4 __attribute__((ext_vector_type(4)));
typedef float f32x4 __attribute__((ext_vector_type(4)));

// ws layout (float offsets)
#define WS_SCALE 0
#define WS_SHIFT 128
#define WS_SUM   256
#define WS_SQ    384
#define WS_ROWSUM 512
#define WS_D     8704
#define WS_HN    16896
#define WS_HX    (WS_HN + NN*IN_DIM)          // f16 [8192][256] in 1M float slots
#define WS_Z     (WS_HX + NN*THETA_DIM)       // 8192*64 f32
#define WS_OBUF  (WS_Z + NN*OUT_DIM)          // 8192*64 f32
#define WS_ZDHT  (WS_OBUF + NN*OUT_DIM)       // f16 [64][8192] in 256K float slots
// total ~17.1 MB

__global__ __launch_bounds__(256) void k_stats(const float* __restrict__ H, float* __restrict__ ws) {
    int tid = threadIdx.x;
    int c = tid & 127, h = tid >> 7;
    int rb = blockIdx.x * 128;
    float s = 0.f, q = 0.f;
    for (int r = h; r < 128; r += 2) {
        float v = H[(size_t)(rb + r) * IN_DIM + c];
        s += v; q += v * v;
    }
    atomicAdd(&ws[WS_SUM + c], s);
    atomicAdd(&ws[WS_SQ + c], q);
}

__global__ void k_finalize(const float* __restrict__ gamma, const float* __restrict__ beta, float* __restrict__ ws) {
    int c = threadIdx.x;  // 128 threads
    float mean = ws[WS_SUM + c] * (1.f / NN);
    float var  = ws[WS_SQ + c] * (1.f / NN) - mean * mean;
    float rstd = 1.f / sqrtf(var + 1e-5f);
    float sc = rstd * gamma[c];
    ws[WS_SCALE + c] = sc;
    ws[WS_SHIFT + c] = beta[c] - mean * sc;
}

__global__ __launch_bounds__(256) void k_hn(const float* __restrict__ H, const float* __restrict__ ws, float* __restrict__ Hn) {
    int i = blockIdx.x * 256 + threadIdx.x;  // f4 index, 262144 total
    const float4* H4 = (const float4*)H;
    float4 v = H4[i];
    int cb = (i & 31) * 4;
    float4 sc = *(const float4*)&ws[WS_SCALE + cb];
    float4 sh = *(const float4*)&ws[WS_SHIFT + cb];
    float4 o;
    o.x = v.x * sc.x + sh.x; o.y = v.y * sc.y + sh.y;
    o.z = v.z * sc.z + sh.z; o.w = v.w * sc.w + sh.w;
    ((float4*)Hn)[i] = o;
}

// Hx = (Hn @ W1 + b1) as f16   [8192,256]
__global__ __launch_bounds__(256) void k_hx(const float* __restrict__ Hn, const float* __restrict__ W1,
                                            const float* __restrict__ b1, half_t* __restrict__ Hx) {
    __shared__ float HnS[32 * IN_DIM];  // 16KB
    int tid = threadIdx.x;
    int row0 = blockIdx.x * 32;
    const float4* src = (const float4*)(Hn + (size_t)row0 * IN_DIM);
    float4* dst = (float4*)HnS;
#pragma unroll
    for (int q = 0; q < 4; q++) dst[q * 256 + tid] = src[q * 256 + tid];
    __syncthreads();
    int c = tid;
    float acc[32];
#pragma unroll
    for (int r = 0; r < 32; r++) acc[r] = 0.f;
    for (int k0 = 0; k0 < IN_DIM; k0 += 4) {
        float w0 = W1[(size_t)(k0 + 0) * THETA_DIM + c];
        float w1 = W1[(size_t)(k0 + 1) * THETA_DIM + c];
        float w2 = W1[(size_t)(k0 + 2) * THETA_DIM + c];
        float w3 = W1[(size_t)(k0 + 3) * THETA_DIM + c];
#pragma unroll
        for (int r = 0; r < 32; r++) {
            float4 h = *(const float4*)&HnS[r * IN_DIM + k0];
            acc[r] += h.x * w0 + h.y * w1 + h.z * w2 + h.w * w3;
        }
    }
    float bb = b1[c];
#pragma unroll
    for (int r = 0; r < 32; r++) Hx[(size_t)(row0 + r) * THETA_DIM + c] = (half_t)(acc[r] + bb);
}

// Y = Hn @ Wout + bout   [8192,64]
__global__ __launch_bounds__(256) void k_y(const float* __restrict__ Hn, const float* __restrict__ Wout,
                                           const float* __restrict__ bout, float* __restrict__ Y) {
    __shared__ float HnS[64 * IN_DIM];  // 32KB
    int tid = threadIdx.x;
    int row0 = blockIdx.x * 64;
    const float4* src = (const float4*)(Hn + (size_t)row0 * IN_DIM);
    float4* dst = (float4*)HnS;
#pragma unroll
    for (int q = 0; q < 8; q++) dst[q * 256 + tid] = src[q * 256 + tid];
    __syncthreads();
    int c = tid & 63, rg = tid >> 6;
    float acc[16];
#pragma unroll
    for (int r = 0; r < 16; r++) acc[r] = 0.f;
    for (int k0 = 0; k0 < IN_DIM; k0 += 4) {
        float w0 = Wout[(size_t)(k0 + 0) * OUT_DIM + c];
        float w1 = Wout[(size_t)(k0 + 1) * OUT_DIM + c];
        float w2 = Wout[(size_t)(k0 + 2) * OUT_DIM + c];
        float w3 = Wout[(size_t)(k0 + 3) * OUT_DIM + c];
#pragma unroll
        for (int r = 0; r < 16; r++) {
            float4 h = *(const float4*)&HnS[(rg * 16 + r) * IN_DIM + k0];
            acc[r] += h.x * w0 + h.y * w1 + h.z * w2 + h.w * w3;
        }
    }
    float bb = bout[c];
#pragma unroll
    for (int r = 0; r < 16; r++) Y[(size_t)(row0 + rg * 16 + r) * OUT_DIM + c] = acc[r] + bb;
}

// scores = sigmoid(Hx @ Hx^T) via f16 MFMA; LDS-staged coalesced epilogue.
__global__ __launch_bounds__(256) void k_scores(const half_t* __restrict__ Hx,
                                                const float* __restrict__ Amat,
                                                float* __restrict__ A1, float* __restrict__ rowsum) {
    __shared__ char smem[36864];
    half_t* As = (half_t*)smem;        // [128][72]
    half_t* Bs = As + 128 * 72;        // [128][72]
    float*  Sf = (float*)smem;         // [64][132] f32 staging (reused post-GEMM)
    int tid = threadIdx.x;
    int row0 = blockIdx.x * 128, col0 = blockIdx.y * 128;
    int lane = tid & 63, wv = tid >> 6;
    int li = lane & 15, lg = lane >> 4;
    int qr = (wv >> 1) * 64, qc = (wv & 1) * 64;

    f32x4 acc[4][4];
#pragma unroll
    for (int t = 0; t < 4; t++)
#pragma unroll
        for (int u = 0; u < 4; u++) acc[t][u] = (f32x4){0.f, 0.f, 0.f, 0.f};

    for (int s = 0; s < 4; s++) {
        int k0 = s * 64;
        f16x8 ra[4], rb[4];
#pragma unroll
        for (int q = 0; q < 4; q++) {
            int un = q * 256 + tid;
            int r = un >> 3, u = un & 7;
            ra[q] = *(const f16x8*)(Hx + (size_t)(row0 + r) * THETA_DIM + k0 + u * 8);
            rb[q] = *(const f16x8*)(Hx + (size_t)(col0 + r) * THETA_DIM + k0 + u * 8);
        }
        __syncthreads();
#pragma unroll
        for (int q = 0; q < 4; q++) {
            int un = q * 256 + tid;
            int r = un >> 3, u = un & 7;
            *(f16x8*)(As + r * 72 + u * 8) = ra[q];
            *(f16x8*)(Bs + r * 72 + u * 8) = rb[q];
        }
        __syncthreads();
#pragma unroll
        for (int kk = 0; kk < 2; kk++) {
            f16x8 af[4], bf[4];
#pragma unroll
            for (int t = 0; t < 4; t++)
                af[t] = *(const f16x8*)(As + (qr + t * 16 + li) * 72 + kk * 32 + lg * 8);
#pragma unroll
            for (int u = 0; u < 4; u++)
                bf[u] = *(const f16x8*)(Bs + (qc + u * 16 + li) * 72 + kk * 32 + lg * 8);
#pragma unroll
            for (int t = 0; t < 4; t++)
#pragma unroll
                for (int u = 0; u < 4; u++)
                    acc[t][u] = __builtin_amdgcn_mfma_f32_16x16x32_f16(af[t], bf[u], acc[t][u], 0, 0, 0);
        }
    }

    // epilogue: two 64x128 passes through LDS, fully coalesced global I/O
#pragma unroll
    for (int p = 0; p < 2; p++) {
        __syncthreads();
        if ((wv >> 1) == p) {
#pragma unroll
            for (int t = 0; t < 4; t++)
#pragma unroll
                for (int u = 0; u < 4; u++)
#pragma unroll
                    for (int r = 0; r < 4; r++)
                        Sf[(t * 16 + lg * 4 + r) * 132 + qc + u * 16 + li] = acc[t][u][r];
        }
        __syncthreads();
#pragma unroll
        for (int q = 0; q < 8; q++) {
            int unit = q * 256 + tid;
            int lr = unit >> 5, c4 = unit & 31;
            int gr = row0 + p * 64 + lr;
            int gc0 = col0 + c4 * 4;
            float4 sv = *(float4*)&Sf[lr * 132 + c4 * 4];
            float4 av = *(const float4*)&Amat[(size_t)gr * NN + gc0];
            float vv[4];
            float sx[4] = {sv.x, sv.y, sv.z, sv.w};
            float ax[4] = {av.x, av.y, av.z, av.w};
#pragma unroll
            for (int jj = 0; jj < 4; jj++) {
                float sg = 1.f / (1.f + __expf(-sx[jj]));
                float m = ceilf(ax[jj] * 1e-5f);
                vv[jj] = fmaxf(sg, 0.1f) * m + ((gr == gc0 + jj) ? 1.f : 0.f);
            }
            float4 wv4; wv4.x = vv[0]; wv4.y = vv[1]; wv4.z = vv[2]; wv4.w = vv[3];
            *(float4*)&A1[(size_t)gr * NN + gc0] = wv4;
            float rp = vv[0] + vv[1] + vv[2] + vv[3];
            rp += __shfl_xor(rp, 1, 64);
            rp += __shfl_xor(rp, 2, 64);
            rp += __shfl_xor(rp, 4, 64);
            rp += __shfl_xor(rp, 8, 64);
            rp += __shfl_xor(rp, 16, 64);
            if ((lane & 31) == 0) atomicAdd(&rowsum[gr], rp);
        }
    }
}

__global__ void k_dvec(float* __restrict__ ws) {
    int i = blockIdx.x * 256 + threadIdx.x;  // 8192
    ws[WS_D + i] = 1.f / sqrtf(ws[WS_ROWSUM + i]);
}

// ZdhT[c][j] = (half)(Z[j][c] * d[j])   [64][8192] f16
__global__ __launch_bounds__(256) void k_scalez(const float* __restrict__ dvec, const float* __restrict__ Z,
                                                half_t* __restrict__ ZdhT) {
    __shared__ float T[64 * 68];
    int tid = threadIdx.x;
    int j0 = blockIdx.x * 64;
#pragma unroll
    for (int q = 0; q < 4; q++) {
        int unit = q * 256 + tid;
        int j = unit >> 4, c4 = (unit & 15) * 4;
        float dj = dvec[j0 + j];
        float4 v = *(const float4*)&Z[(size_t)(j0 + j) * OUT_DIM + c4];
        v.x *= dj; v.y *= dj; v.z *= dj; v.w *= dj;
        *(float4*)&T[j * 68 + c4] = v;
    }
    __syncthreads();
#pragma unroll
    for (int q = 0; q < 2; q++) {
        int unit = q * 256 + tid;
        int c = unit >> 3, j8 = (unit & 7) * 8;
        f16x8 h;
#pragma unroll
        for (int x = 0; x < 8; x++) h[x] = (half_t)T[(j8 + x) * 68 + c];
        *(f16x8*)&ZdhT[(size_t)c * NN + j0 + j8] = h;
    }
}

// obuf += A1[rows, kslice] @ ZdhT^T   via f16 MFMA. M=128, N=64, K-split 8.
__global__ __launch_bounds__(256) void k_spmm(const float* __restrict__ A1, const half_t* __restrict__ ZdhT,
                                              float* __restrict__ obuf) {
    __shared__ half_t As[128 * 72];  // A1 tile f16 [128 rows][64 k + pad]
    __shared__ half_t Bs[64 * 72];   // ZdhT tile [64 n][64 k + pad]
    int tid = threadIdx.x;
    int row0 = blockIdx.x * 128;
    int j0 = blockIdx.y * 1024;
    int lane = tid & 63, wv = tid >> 6;
    int li = lane & 15, lg = lane >> 4;

    f32x4 acc[2][4];
#pragma unroll
    for (int t = 0; t < 2; t++)
#pragma unroll
        for (int u = 0; u < 4; u++) acc[t][u] = (f32x4){0.f, 0.f, 0.f, 0.f};

    for (int jc = j0; jc < j0 + 1024; jc += 64) {
        __syncthreads();
#pragma unroll
        for (int q = 0; q < 8; q++) {
            int unit = q * 256 + tid;
            int r = unit >> 4, c4 = (unit & 15) * 4;
            float4 v = *(const float4*)&A1[(size_t)(row0 + r) * NN + jc + c4];
            f16x4 h; h[0] = (half_t)v.x; h[1] = (half_t)v.y; h[2] = (half_t)v.z; h[3] = (half_t)v.w;
            *(f16x4*)&As[r * 72 + c4] = h;
        }
#pragma unroll
        for (int q = 0; q < 2; q++) {
            int unit = q * 256 + tid;
            int n = unit >> 3, k8 = (unit & 7) * 8;
            *(f16x8*)&Bs[n * 72 + k8] = *(const f16x8*)&ZdhT[(size_t)n * NN + jc + k8];
        }
        __syncthreads();
#pragma unroll
        for (int kk = 0; kk < 2; kk++) {
            f16x8 af[2], bf[4];
#pragma unroll
            for (int t = 0; t < 2; t++)
                af[t] = *(const f16x8*)&As[(wv * 32 + t * 16 + li) * 72 + kk * 32 + lg * 8];
#pragma unroll
            for (int u = 0; u < 4; u++)
                bf[u] = *(const f16x8*)&Bs[(u * 16 + li) * 72 + kk * 32 + lg * 8];
#pragma unroll
            for (int t = 0; t < 2; t++)
#pragma unroll
                for (int u = 0; u < 4; u++)
                    acc[t][u] = __builtin_amdgcn_mfma_f32_16x16x32_f16(af[t], bf[u], acc[t][u], 0, 0, 0);
        }
    }
#pragma unroll
    for (int t = 0; t < 2; t++)
#pragma unroll
        for (int u = 0; u < 4; u++)
#pragma unroll
            for (int r = 0; r < 4; r++)
                atomicAdd(&obuf[(size_t)(row0 + wv * 32 + t * 16 + lg * 4 + r) * OUT_DIM + u * 16 + li],
                          acc[t][u][r]);
}

__global__ void k_out(const float* __restrict__ ws, float* __restrict__ out) {
    int i = blockIdx.x * 256 + threadIdx.x;  // f4 over 524288 -> 131072
    const float4* O4 = (const float4*)(ws + WS_OBUF);
    int row = i >> 4;
    float d = ws[WS_D + row];
    float4 v = O4[i];
    float a = d * v.x, b = d * v.y, cc = d * v.z, e = d * v.w;
    v.x = (a >= 0.f) ? a : 0.01f * a;
    v.y = (b >= 0.f) ? b : 0.01f * b;
    v.z = (cc >= 0.f) ? cc : 0.01f * cc;
    v.w = (e >= 0.f) ? e : 0.01f * e;
    ((float4*)out)[i] = v;
}

extern "C" void kernel_launch(void* const* d_in, const int* in_sizes, int n_in,
                              void* d_out, int out_size, void* d_ws, size_t ws_size,
                              hipStream_t stream) {
    const float* H     = (const float*)d_in[0];
    const float* A     = (const float*)d_in[1];
    const float* gamma = (const float*)d_in[2];
    const float* beta  = (const float*)d_in[3];
    const float* W1    = (const float*)d_in[4];
    const float* b1    = (const float*)d_in[5];
    const float* Wout  = (const float*)d_in[6];
    const float* bout  = (const float*)d_in[7];
    float* out = (float*)d_out;
    float* A1  = out + (size_t)NN * OUT_DIM;
    float* ws  = (float*)d_ws;
    half_t* Hx = (half_t*)(ws + WS_HX);
    half_t* ZdhT = (half_t*)(ws + WS_ZDHT);

    hipMemsetAsync(ws + WS_SUM, 0, (WS_D - WS_SUM) * sizeof(float), stream);
    hipMemsetAsync(ws + WS_OBUF, 0, (size_t)NN * OUT_DIM * sizeof(float), stream);

    k_stats<<<64, 256, 0, stream>>>(H, ws);
    k_finalize<<<1, 128, 0, stream>>>(gamma, beta, ws);
    k_hn<<<1024, 256, 0, stream>>>(H, ws, ws + WS_HN);
    k_hx<<<256, 256, 0, stream>>>(ws + WS_HN, W1, b1, Hx);
    k_y<<<128, 256, 0, stream>>>(ws + WS_HN, Wout, bout, ws + WS_Z);
    dim3 g6(64, 64);
    k_scores<<<g6, 256, 0, stream>>>(Hx, A, A1, ws + WS_ROWSUM);
    k_dvec<<<32, 256, 0, stream>>>(ws);
    k_scalez<<<128, 256, 0, stream>>>(ws + WS_D, ws + WS_Z, ZdhT);
    k_spmm<<<dim3(64, 8), 256, 0, stream>>>(A1, ZdhT, ws + WS_OBUF);
    k_out<<<512, 256, 0, stream>>>(ws, out);
}